// Round 1
// baseline (1469.853 us; speedup 1.0000x reference)
//
#include <hip/hip_runtime.h>
#include <math.h>

#define W 128
#define NANG 128
#define SZ 128
#define NV 8
#define NROWS 2048   // B*C*H = 2*8*128
#define OUT_SCALE 0.012271846303085130f   // pi / (2*128)

// ws layout:
//   [0,    512): filter taps k[128] (f32)
//   [512, 1536): cos/sin table, 128 x float2
//   [4096, 4096+8MiB): filtered projections Pf[2048][8][128] f32

struct Ptrs8 { const float* p[8]; };

// ---- kernel 0: build filter taps + trig tables (1 block, 128 threads) ----
__global__ void k_tables(float* __restrict__ kt, float2* __restrict__ cs) {
    int d = threadIdx.x;
    // k[d] = (1/128) * sum_f |fftfreq(f)| * cos(2*pi*f*d/128)
    double s = 0.0;
    for (int f = 0; f < W; ++f) {
        double ramp = (double)(f < W - f ? f : W - f) / (double)W;
        s += ramp * cos(2.0 * M_PI * (double)(f * d) / (double)W);
    }
    kt[d] = (float)(s / (double)W);
    double th = (double)d * M_PI / (double)NANG;
    cs[d] = make_float2((float)cos(th), (float)sin(th));
}

// ---- kernel 1: Ram-Lak circular conv per (row, view) ----
// grid = NROWS*NV blocks, 128 threads; blk = r*8 + v
__global__ void k_filter(Ptrs8 in, const float* __restrict__ kt,
                         float* __restrict__ pf) {
    int blk = blockIdx.x;
    int r = blk >> 3, v = blk & 7;
    __shared__ float row[W];
    __shared__ float kk[W];
    int n = threadIdx.x;
    row[n] = in.p[v][r * W + n];
    kk[n]  = kt[n];
    __syncthreads();
    float s = 0.f;
#pragma unroll 8
    for (int m = 0; m < W; ++m) {
        s = fmaf(row[m], kk[(n - m) & (W - 1)], s);
    }
    pf[(r * NV + v) * W + n] = s;
}

// ---- kernel 2: angle-resize into LDS sinogram + back-projection ----
// grid = NROWS blocks (one per b,c,h), 256 threads
__global__ __launch_bounds__(256, 2)
void k_backproject(const float* __restrict__ pf, const float2* __restrict__ cs,
                   float* __restrict__ out) {
    __shared__ float sino[NANG * W];   // exactly 64 KiB
    const int r   = blockIdx.x;
    const int tid = threadIdx.x;

    // Build interpolated sinogram: sino[a][w] = lerp over views at angle a.
    // jax.image.resize(linear, half-pixel) == clamp-to-edge linear interp.
    for (int idx = tid; idx < NANG * W; idx += 256) {
        int a = idx >> 7, w = idx & (W - 1);
        float src = (a + 0.5f) * 0.0625f - 0.5f;        // (a+0.5)*8/128 - 0.5
        float sf  = fminf(fmaxf(src, 0.f), 7.f);
        float v0f = floorf(sf);
        int   v0  = (int)v0f;
        int   v1  = v0 + 1 < NV ? v0 + 1 : NV - 1;
        float wa  = sf - v0f;
        float p0 = pf[(r * NV + v0) * W + w];
        float p1 = pf[(r * NV + v1) * W + w];
        sino[idx] = fmaf(wa, p1 - p0, p0);
    }
    __syncthreads();

    // Back-projection. Wave-uniform y per iteration -> lane gather stride
    // = cos(theta) <= 1 -> <=2-way LDS bank aliasing (free).
    const int wave = tid >> 6, lane = tid & 63;
    const float xj0 = (float)lane - 63.5f;
    const float xj1 = (float)lane + 0.5f;          // lane + 64 - 63.5
    float* outr = out + (size_t)r * (SZ * SZ);

    for (int iy = 0; iy < 32; ++iy) {
        const int i = wave * 32 + iy;
        const float ys = (float)i - 63.5f;
        float acc0 = 0.f, acc1 = 0.f;
        for (int a = 0; a < NANG; ++a) {
            const float2 csa = cs[a];               // wave-uniform -> s_load
            const float base = fmaf(ys, csa.y, 63.5f);
            const float* rowp = &sino[a * W];
            // pixel (i, lane)
            {
                float t  = fmaf(xj0, csa.x, base);
                t        = fminf(fmaxf(t, 0.f), 127.f);
                float tf = fminf(floorf(t), 126.f); // so ti+1 <= 127
                int   ti = (int)tf;
                float wt = t - tf;
                float v0 = rowp[ti], v1 = rowp[ti + 1];
                acc0 = fmaf(wt, v1 - v0, acc0 + v0);
            }
            // pixel (i, lane+64)
            {
                float t  = fmaf(xj1, csa.x, base);
                t        = fminf(fmaxf(t, 0.f), 127.f);
                float tf = fminf(floorf(t), 126.f);
                int   ti = (int)tf;
                float wt = t - tf;
                float v0 = rowp[ti], v1 = rowp[ti + 1];
                acc1 = fmaf(wt, v1 - v0, acc1 + v0);
            }
        }
        outr[i * SZ + lane]      = acc0 * OUT_SCALE;
        outr[i * SZ + lane + 64] = acc1 * OUT_SCALE;
    }
}

extern "C" void kernel_launch(void* const* d_in, const int* in_sizes, int n_in,
                              void* d_out, int out_size, void* d_ws, size_t ws_size,
                              hipStream_t stream) {
    float*  kt = (float*)d_ws;
    float2* cs = (float2*)((char*)d_ws + 512);
    float*  pf = (float*)((char*)d_ws + 4096);

    Ptrs8 in;
    for (int i = 0; i < NV; ++i) in.p[i] = (const float*)d_in[i];

    k_tables<<<1, 128, 0, stream>>>(kt, cs);
    k_filter<<<NROWS * NV, 128, 0, stream>>>(in, kt, pf);
    k_backproject<<<NROWS, 256, 0, stream>>>(pf, cs, (float*)d_out);
}

// Round 2
// 337.348 us; speedup vs baseline: 4.3571x; 4.3571x over previous
//
#include <hip/hip_runtime.h>
#include <math.h>

#define W 128
#define NANG 128
#define SZ 128
#define NV 8
#define NROWS 2048          // B*C*H
#define K_DIM 1024          // NV * W
#define NPIX 16384          // SZ * SZ
#define OUT_SCALE 0.012271846303085130f   // pi / 256

typedef _Float16 f16x8 __attribute__((ext_vector_type(8)));
typedef float    f32x4 __attribute__((ext_vector_type(4)));

// ws layout:
//   [0, 512)                 : filter taps k[128] f32
//   [512, 1536)              : cos/sin table float2[128]
//   [4096, 4096+4MiB)        : Pf  f16 [2048 rows][1024 k]   (k = v*128 + t)
//   [4096+4MiB, +32MiB)      : WvT f16 [16384 pix][1024 k]

struct Ptrs8 { const float* p[8]; };

__device__ __forceinline__ void glds16(const void* g, void* l) {
    __builtin_amdgcn_global_load_lds(
        (const __attribute__((address_space(1))) void*)g,
        (__attribute__((address_space(3))) void*)l, 16, 0, 0);
}

// ---- kernel 0: filter taps + trig tables ----
__global__ void k_tables(float* __restrict__ kt, float2* __restrict__ cs) {
    int d = threadIdx.x;
    double s = 0.0;
    for (int f = 0; f < W; ++f) {
        double ramp = (double)(f < W - f ? f : W - f) / (double)W;
        s += ramp * cos(2.0 * M_PI * (double)(f * d) / (double)W);
    }
    kt[d] = (float)(s / (double)W);
    double th = (double)d * M_PI / (double)NANG;
    cs[d] = make_float2((float)cos(th), (float)sin(th));
}

// ---- kernel 1: Ram-Lak circular conv per (row, view), f16 output ----
// grid = NROWS*NV, 128 threads; blk = r*8 + v; out Pf[r][v*128 + n]
__global__ void k_filter(Ptrs8 in, const float* __restrict__ kt,
                         _Float16* __restrict__ pf) {
    int blk = blockIdx.x;
    int r = blk >> 3, v = blk & 7;
    __shared__ float row[W];
    __shared__ float kk[W];
    int n = threadIdx.x;
    row[n] = in.p[v][r * W + n];
    kk[n]  = kt[n];
    __syncthreads();
    float s = 0.f;
#pragma unroll 8
    for (int m = 0; m < W; ++m)
        s = fmaf(row[m], kk[(n - m) & (W - 1)], s);
    pf[(size_t)r * K_DIM + v * W + n] = (_Float16)s;
}

// ---- kernel 2: build Wv[pixel][k] : fused angle-lerp x detector-lerp weights ----
// grid = NPIX/8 blocks, 256 threads; 8 pixels per block, LDS 32 KiB
__global__ void k_wv(const float2* __restrict__ cs, _Float16* __restrict__ wv) {
    __shared__ float wrow[8 * K_DIM];
    const int tid = threadIdx.x;
    const int p0 = blockIdx.x * 8;
    for (int i = tid; i < 8 * K_DIM; i += 256) wrow[i] = 0.f;
    __syncthreads();
    const int px  = tid >> 5;     // 0..7
    const int sub = tid & 31;     // 32 threads per pixel
    const int p = p0 + px;
    const float x = (float)(p & 127) - 63.5f;   // j (fast dim) -> cos
    const float y = (float)(p >> 7) - 63.5f;    // i (slow dim) -> sin
    float* prow = &wrow[px * K_DIM];
    for (int a = sub; a < NANG; a += 32) {
        float2 c = cs[a];
        float t = fmaf(x, c.x, fmaf(y, c.y, 63.5f));
        t = fminf(fmaxf(t, 0.f), 127.f);
        float tf = fminf(floorf(t), 126.f);
        int   ti = (int)tf;
        float wt = t - tf;
        float src = ((float)a + 0.5f) * 0.0625f - 0.5f;
        src = fminf(fmaxf(src, 0.f), 7.f);
        float vf = floorf(src);
        int   v0 = (int)vf;
        int   v1 = v0 + 1 < NV ? v0 + 1 : NV - 1;
        float wa = src - vf;
        float wA0 = (1.f - wa) * OUT_SCALE;
        atomicAdd(&prow[v0 * W + ti],     wA0 * (1.f - wt));
        atomicAdd(&prow[v0 * W + ti + 1], wA0 * wt);
        if (v1 != v0) {   // when v1==v0, wa==0 -> nothing to add
            float wA1 = wa * OUT_SCALE;
            atomicAdd(&prow[v1 * W + ti],     wA1 * (1.f - wt));
            atomicAdd(&prow[v1 * W + ti + 1], wA1 * wt);
        }
    }
    __syncthreads();
    for (int i = tid; i < 8 * K_DIM; i += 256) {
        int pp = i >> 10, kk2 = i & 1023;
        wv[(size_t)(p0 + pp) * K_DIM + kk2] = (_Float16)wrow[i];
    }
}

// ---- kernel 3: GEMM  Out[m=row][n=pixel] = sum_k Pf[m][k] * Wv[n][k] ----
// BM=BN=128, BK=32, 256 threads = 4 waves, each wave 64x64 (4x4 16x16 tiles)
__global__ __launch_bounds__(256)
void k_gemm(const _Float16* __restrict__ A,   // Pf  [NROWS][K_DIM]
            const _Float16* __restrict__ B,   // WvT [NPIX][K_DIM]
            float* __restrict__ out) {        // [NROWS][NPIX]
    __shared__ _Float16 sA[128 * 32];
    __shared__ _Float16 sB[128 * 32];
    const int tid  = threadIdx.x;
    const int lane = tid & 63, wave = tid >> 6;
    const int m0 = blockIdx.y * 128;
    const int n0 = blockIdx.x * 128;
    const int wm = wave >> 1, wn = wave & 1;

    f32x4 acc[4][4] = {};

    // staging: 512 16B-chunks per tile; chunk c: row=c>>2, g=c&3 (identity LDS layout)
    const int c0 = wave * 64 + lane;
    const int c1 = c0 + 256;
    const _Float16* gA0 = A + (size_t)(m0 + (c0 >> 2)) * K_DIM + (c0 & 3) * 8;
    const _Float16* gA1 = A + (size_t)(m0 + (c1 >> 2)) * K_DIM + (c1 & 3) * 8;
    const _Float16* gB0 = B + (size_t)(n0 + (c0 >> 2)) * K_DIM + (c0 & 3) * 8;
    const _Float16* gB1 = B + (size_t)(n0 + (c1 >> 2)) * K_DIM + (c1 & 3) * 8;
    _Float16* lA0 = sA + wave * 512;          // halfs; HW adds lane*16B
    _Float16* lA1 = sA + 2048 + wave * 512;
    _Float16* lB0 = sB + wave * 512;
    _Float16* lB1 = sB + 2048 + wave * 512;

    const int fr = lane & 15;   // m/n within 16-tile
    const int fg = lane >> 4;   // k-chunk (8 halfs)

    for (int kb = 0; kb < K_DIM; kb += 32) {
        glds16(gA0 + kb, lA0);
        glds16(gA1 + kb, lA1);
        glds16(gB0 + kb, lB0);
        glds16(gB1 + kb, lB1);
        __syncthreads();
        f16x8 af[4], bf[4];
#pragma unroll
        for (int mt = 0; mt < 4; ++mt)
            af[mt] = *(const f16x8*)&sA[((wm * 4 + mt) * 16 + fr) * 32 + fg * 8];
#pragma unroll
        for (int nt = 0; nt < 4; ++nt)
            bf[nt] = *(const f16x8*)&sB[((wn * 4 + nt) * 16 + fr) * 32 + fg * 8];
#pragma unroll
        for (int mt = 0; mt < 4; ++mt)
#pragma unroll
            for (int nt = 0; nt < 4; ++nt)
                acc[mt][nt] = __builtin_amdgcn_mfma_f32_16x16x32_f16(
                    af[mt], bf[nt], acc[mt][nt], 0, 0, 0);
        __syncthreads();
    }

    // C/D layout: col = lane&15 (n), row = (lane>>4)*4 + reg (m)
#pragma unroll
    for (int mt = 0; mt < 4; ++mt) {
#pragma unroll
        for (int nt = 0; nt < 4; ++nt) {
            int m = m0 + (wm * 4 + mt) * 16 + fg * 4;
            int n = n0 + (wn * 4 + nt) * 16 + fr;
            float* op = out + (size_t)m * NPIX + n;
#pragma unroll
            for (int rr = 0; rr < 4; ++rr)
                op[(size_t)rr * NPIX] = acc[mt][nt][rr];
        }
    }
}

extern "C" void kernel_launch(void* const* d_in, const int* in_sizes, int n_in,
                              void* d_out, int out_size, void* d_ws, size_t ws_size,
                              hipStream_t stream) {
    float*      kt = (float*)d_ws;
    float2*     cs = (float2*)((char*)d_ws + 512);
    _Float16*   pf = (_Float16*)((char*)d_ws + 4096);
    _Float16*   wv = (_Float16*)((char*)d_ws + 4096 + (size_t)NROWS * K_DIM * 2);

    Ptrs8 in;
    for (int i = 0; i < NV; ++i) in.p[i] = (const float*)d_in[i];

    k_tables<<<1, 128, 0, stream>>>(kt, cs);
    k_filter<<<NROWS * NV, 128, 0, stream>>>(in, kt, pf);
    k_wv<<<NPIX / 8, 256, 0, stream>>>(cs, wv);
    dim3 grid(NPIX / 128, NROWS / 128);
    k_gemm<<<grid, 256, 0, stream>>>(pf, wv, (float*)d_out);
}

// Round 3
// 313.986 us; speedup vs baseline: 4.6813x; 1.0744x over previous
//
#include <hip/hip_runtime.h>
#include <math.h>

#define W 128
#define NANG 128
#define SZ 128
#define NV 8
#define NROWS 2048          // B*C*H
#define K_DIM 1024          // NV * W
#define NPIX 16384          // SZ * SZ
#define OUT_SCALE 0.012271846303085130f   // pi / 256

typedef _Float16 f16x8 __attribute__((ext_vector_type(8)));
typedef float    f32x4 __attribute__((ext_vector_type(4)));

// ws layout:
//   [0, 512)                 : filter taps k[128] f32
//   [512, 1536)              : cos/sin table float2[128]
//   [4096, 4096+4MiB)        : Pf  f16 [2048 rows][1024 k]   (k = v*128 + t)
//   [4096+4MiB, +32MiB)      : WvT f16 [16384 pix][1024 k]

struct Ptrs8 { const float* p[8]; };

__device__ __forceinline__ void glds16(const void* g, void* l) {
    __builtin_amdgcn_global_load_lds(
        (const __attribute__((address_space(1))) void*)g,
        (__attribute__((address_space(3))) void*)l, 16, 0, 0);
}

// ---- kernel 0: filter taps + trig tables (f32 — matches reference's f32 trig) ----
// k[d] = (1/W^2) * [ 2*sum_{f=1..63} f*cos(2*pi*f*d/W) + 64*cos(pi*d) ]
__global__ void k_tables(float* __restrict__ kt, float2* __restrict__ cs) {
    int d = threadIdx.x;
    const float w0 = 6.283185307179586f / (float)W * (float)d;  // 2*pi*d/W
    float s = 0.f;
    for (int f = 1; f < 64; ++f)
        s = fmaf((float)f, __cosf(w0 * (float)f), s);
    s = 2.f * s + 64.f * ((d & 1) ? -1.f : 1.f);   // cos(pi*d) = +/-1
    kt[d] = s * (1.f / (float)(W * W));
    float th = (float)d * ((float)M_PI / (float)NANG);
    cs[d] = make_float2(cosf(th), sinf(th));
}

// ---- kernel 1: Ram-Lak circular conv per (row, view), f16 output ----
// grid = NROWS*NV, 128 threads; blk = r*8 + v; out Pf[r][v*128 + n]
__global__ void k_filter(Ptrs8 in, const float* __restrict__ kt,
                         _Float16* __restrict__ pf) {
    int blk = blockIdx.x;
    int r = blk >> 3, v = blk & 7;
    __shared__ float row[W];
    __shared__ float kk[W];
    int n = threadIdx.x;
    row[n] = in.p[v][r * W + n];
    kk[n]  = kt[n];
    __syncthreads();
    float s = 0.f;
#pragma unroll 8
    for (int m = 0; m < W; ++m)
        s = fmaf(row[m], kk[(n - m) & (W - 1)], s);
    pf[(size_t)r * K_DIM + v * W + n] = (_Float16)s;
}

// ---- kernel 2: build Wv[pixel][k] : fused angle-lerp x detector-lerp weights ----
// grid = NPIX/8 blocks, 256 threads; 8 pixels per block, LDS 32 KiB
__global__ void k_wv(const float2* __restrict__ cs, _Float16* __restrict__ wv) {
    __shared__ float wrow[8 * K_DIM];
    const int tid = threadIdx.x;
    const int p0 = blockIdx.x * 8;
    for (int i = tid; i < 8 * K_DIM; i += 256) wrow[i] = 0.f;
    __syncthreads();
    const int px  = tid >> 5;     // 0..7
    const int sub = tid & 31;     // 32 threads per pixel
    const int p = p0 + px;
    const float x = (float)(p & 127) - 63.5f;   // j (fast dim) -> cos
    const float y = (float)(p >> 7) - 63.5f;    // i (slow dim) -> sin
    float* prow = &wrow[px * K_DIM];
    for (int a = sub; a < NANG; a += 32) {
        float2 c = cs[a];
        float t = fmaf(x, c.x, fmaf(y, c.y, 63.5f));
        t = fminf(fmaxf(t, 0.f), 127.f);
        float tf = fminf(floorf(t), 126.f);
        int   ti = (int)tf;
        float wt = t - tf;
        float src = ((float)a + 0.5f) * 0.0625f - 0.5f;
        src = fminf(fmaxf(src, 0.f), 7.f);
        float vf = floorf(src);
        int   v0 = (int)vf;
        int   v1 = v0 + 1 < NV ? v0 + 1 : NV - 1;
        float wa = src - vf;
        float wA0 = (1.f - wa) * OUT_SCALE;
        atomicAdd(&prow[v0 * W + ti],     wA0 * (1.f - wt));
        atomicAdd(&prow[v0 * W + ti + 1], wA0 * wt);
        if (v1 != v0) {   // when v1==v0, wa==0 -> nothing to add
            float wA1 = wa * OUT_SCALE;
            atomicAdd(&prow[v1 * W + ti],     wA1 * (1.f - wt));
            atomicAdd(&prow[v1 * W + ti + 1], wA1 * wt);
        }
    }
    __syncthreads();
    for (int i = tid; i < 8 * K_DIM; i += 256) {
        int pp = i >> 10, kk2 = i & 1023;
        wv[(size_t)(p0 + pp) * K_DIM + kk2] = (_Float16)wrow[i];
    }
}

// ---- kernel 3: GEMM  Out[m=row][n=pixel] = sum_k Pf[m][k] * Wv[n][k] ----
// BM=BN=128, BK=32, 256 threads = 4 waves, each wave 64x64 (4x4 16x16 tiles)
__global__ __launch_bounds__(256)
void k_gemm(const _Float16* __restrict__ A,   // Pf  [NROWS][K_DIM]
            const _Float16* __restrict__ B,   // WvT [NPIX][K_DIM]
            float* __restrict__ out) {        // [NROWS][NPIX]
    __shared__ _Float16 sA[128 * 32];
    __shared__ _Float16 sB[128 * 32];
    const int tid  = threadIdx.x;
    const int lane = tid & 63, wave = tid >> 6;
    const int m0 = blockIdx.y * 128;
    const int n0 = blockIdx.x * 128;
    const int wm = wave >> 1, wn = wave & 1;

    f32x4 acc[4][4] = {};

    // staging: 512 16B-chunks per tile; chunk c: row=c>>2, g=c&3 (identity LDS layout)
    const int c0 = wave * 64 + lane;
    const int c1 = c0 + 256;
    const _Float16* gA0 = A + (size_t)(m0 + (c0 >> 2)) * K_DIM + (c0 & 3) * 8;
    const _Float16* gA1 = A + (size_t)(m0 + (c1 >> 2)) * K_DIM + (c1 & 3) * 8;
    const _Float16* gB0 = B + (size_t)(n0 + (c0 >> 2)) * K_DIM + (c0 & 3) * 8;
    const _Float16* gB1 = B + (size_t)(n0 + (c1 >> 2)) * K_DIM + (c1 & 3) * 8;
    _Float16* lA0 = sA + wave * 512;          // halfs; HW adds lane*16B
    _Float16* lA1 = sA + 2048 + wave * 512;
    _Float16* lB0 = sB + wave * 512;
    _Float16* lB1 = sB + 2048 + wave * 512;

    const int fr = lane & 15;   // m/n within 16-tile
    const int fg = lane >> 4;   // k-chunk (8 halfs)

    for (int kb = 0; kb < K_DIM; kb += 32) {
        glds16(gA0 + kb, lA0);
        glds16(gA1 + kb, lA1);
        glds16(gB0 + kb, lB0);
        glds16(gB1 + kb, lB1);
        __syncthreads();
        f16x8 af[4], bf[4];
#pragma unroll
        for (int mt = 0; mt < 4; ++mt)
            af[mt] = *(const f16x8*)&sA[((wm * 4 + mt) * 16 + fr) * 32 + fg * 8];
#pragma unroll
        for (int nt = 0; nt < 4; ++nt)
            bf[nt] = *(const f16x8*)&sB[((wn * 4 + nt) * 16 + fr) * 32 + fg * 8];
#pragma unroll
        for (int mt = 0; mt < 4; ++mt)
#pragma unroll
            for (int nt = 0; nt < 4; ++nt)
                acc[mt][nt] = __builtin_amdgcn_mfma_f32_16x16x32_f16(
                    af[mt], bf[nt], acc[mt][nt], 0, 0, 0);
        __syncthreads();
    }

    // C/D layout: col = lane&15 (n), row = (lane>>4)*4 + reg (m)
#pragma unroll
    for (int mt = 0; mt < 4; ++mt) {
#pragma unroll
        for (int nt = 0; nt < 4; ++nt) {
            int m = m0 + (wm * 4 + mt) * 16 + fg * 4;
            int n = n0 + (wn * 4 + nt) * 16 + fr;
            float* op = out + (size_t)m * NPIX + n;
#pragma unroll
            for (int rr = 0; rr < 4; ++rr)
                op[(size_t)rr * NPIX] = acc[mt][nt][rr];
        }
    }
}

extern "C" void kernel_launch(void* const* d_in, const int* in_sizes, int n_in,
                              void* d_out, int out_size, void* d_ws, size_t ws_size,
                              hipStream_t stream) {
    float*      kt = (float*)d_ws;
    float2*     cs = (float2*)((char*)d_ws + 512);
    _Float16*   pf = (_Float16*)((char*)d_ws + 4096);
    _Float16*   wv = (_Float16*)((char*)d_ws + 4096 + (size_t)NROWS * K_DIM * 2);

    Ptrs8 in;
    for (int i = 0; i < NV; ++i) in.p[i] = (const float*)d_in[i];

    k_tables<<<1, 128, 0, stream>>>(kt, cs);
    k_filter<<<NROWS * NV, 128, 0, stream>>>(in, kt, pf);
    k_wv<<<NPIX / 8, 256, 0, stream>>>(cs, wv);
    dim3 grid(NPIX / 128, NROWS / 128);
    k_gemm<<<grid, 256, 0, stream>>>(pf, wv, (float*)d_out);
}

// Round 4
// 294.576 us; speedup vs baseline: 4.9897x; 1.0659x over previous
//
#include <hip/hip_runtime.h>
#include <math.h>

#define W 128
#define NANG 128
#define SZ 128
#define NV 8
#define NROWS 2048          // B*C*H
#define K_DIM 1024          // NV * W
#define NPIX 16384          // SZ * SZ
#define OUT_SCALE 0.012271846303085130f   // pi / 256

typedef _Float16 f16x8 __attribute__((ext_vector_type(8)));
typedef _Float16 f16x4 __attribute__((ext_vector_type(4)));
typedef float    f32x4 __attribute__((ext_vector_type(4)));

// ws layout:
//   [0, 512)        : filter taps kt[128] f32
//   [512, 1536)     : cos/sin table float2[128]
//   [4096, 36864)   : Cf16 circulant [t][s] f16 128x128 (32 KiB)
//   [36864, +4MiB)  : Pf  f16 [2048 r][8 v][128 t]
//   [.., +32MiB)    : Wv  f16 [16384 pix][1024 k]
#define CF_OFF 4096
#define PF_OFF 36864
#define WV_OFF (36864 + (size_t)NROWS * K_DIM * 2)

struct Ptrs8 { const float* p[8]; };

__device__ __forceinline__ void glds16(const void* g, void* l) {
    __builtin_amdgcn_global_load_lds(
        (const __attribute__((address_space(1))) void*)g,
        (__attribute__((address_space(3))) void*)l, 16, 0, 0);
}

// ---- kernel 0: filter taps + trig tables + f16 circulant matrix ----
// kt[d] = (1/W^2) * [ 2*sum_{f=1..63} f*cos(2*pi*f*d/W) + 64*cos(pi*d) ]
__global__ void k_tables(float* __restrict__ kt, float2* __restrict__ cs,
                         _Float16* __restrict__ cf) {
    __shared__ float kl[W];
    int d = threadIdx.x;
    const float w0 = 6.283185307179586f / (float)W * (float)d;
    float s = 0.f;
    for (int f = 1; f < 64; ++f)
        s = fmaf((float)f, __cosf(w0 * (float)f), s);
    s = 2.f * s + 64.f * ((d & 1) ? -1.f : 1.f);
    float kv = s * (1.f / (float)(W * W));
    kt[d] = kv;
    kl[d] = kv;
    float th = (float)d * ((float)M_PI / (float)NANG);
    cs[d] = make_float2(cosf(th), sinf(th));
    __syncthreads();
    // Cf16[t][s] = kt[(t-s)&127], row t = thread d
    for (int k = 0; k < W; ++k)
        cf[d * W + k] = (_Float16)kl[(d - k) & (W - 1)];
}

// ---- kernel 1: filter as MFMA GEMM with fused f32->f16 cast ----
// Pf[(r,v)][t] = sum_s In[v][r][s] * C[t][s].  Grid: 256 blocks, 64 rows each.
// Tile rows: m = blk*64 + i*8 + v  ->  r = blk*8 + i (i=0..7), v=0..7.
#define FS_A 136   // padded LDS row stride (halfs): +8 -> 2-way bank alias only
__global__ __launch_bounds__(256)
void k_fgemm(Ptrs8 in, const _Float16* __restrict__ cf,
             _Float16* __restrict__ pf) {
    __shared__ _Float16 sA[64 * FS_A];
    __shared__ _Float16 sB[128 * FS_A];
    const int tid  = threadIdx.x;
    const int lane = tid & 63, wave = tid >> 6;
    const int fr = lane & 15, fg = lane >> 4;
    const int blk = blockIdx.x;

    // stage A: per view v, 8 rows x 128 f32 -> f16
    {
        const int i   = tid >> 5;          // row-within-view-group 0..7
        const int pos = (tid & 31) * 4;    // f32 position 0..124
#pragma unroll
        for (int v = 0; v < NV; ++v) {
            float4 x = *(const float4*)(in.p[v] + (size_t)(blk * 8 + i) * W + pos);
            f16x4 h = { (_Float16)x.x, (_Float16)x.y, (_Float16)x.z, (_Float16)x.w };
            *(f16x4*)&sA[(i * 8 + v) * FS_A + pos] = h;
        }
    }
    // stage B: circulant 128x128 f16, padded rows
#pragma unroll
    for (int j = 0; j < 8; ++j) {
        int c = tid + 256 * j;             // 2048 chunks of 8 halfs
        int n = c >> 4, kp = (c & 15) * 8;
        *(f16x8*)&sB[n * FS_A + kp] = *(const f16x8*)&cf[n * W + kp];
    }
    __syncthreads();

    f32x4 acc[8] = {};
#pragma unroll
    for (int kb = 0; kb < W; kb += 32) {
        f16x8 af = *(const f16x8*)&sA[(wave * 16 + fr) * FS_A + kb + fg * 8];
#pragma unroll
        for (int nt = 0; nt < 8; ++nt) {
            f16x8 bf = *(const f16x8*)&sB[(nt * 16 + fr) * FS_A + kb + fg * 8];
            acc[nt] = __builtin_amdgcn_mfma_f32_16x16x32_f16(af, bf, acc[nt], 0, 0, 0);
        }
    }
    // C/D: col = fr (t), row = fg*4 + rr (m within 16)
#pragma unroll
    for (int nt = 0; nt < 8; ++nt) {
        int m = blk * 64 + wave * 16 + fg * 4;
        int n = nt * 16 + fr;
#pragma unroll
        for (int rr = 0; rr < 4; ++rr)
            pf[(size_t)(m + rr) * W + n] = (_Float16)acc[nt][rr];
    }
}

// ---- kernel 2: build Wv[pixel][k] : fused angle-lerp x detector-lerp weights ----
__global__ void k_wv(const float2* __restrict__ cs, _Float16* __restrict__ wv) {
    __shared__ float wrow[8 * K_DIM];
    const int tid = threadIdx.x;
    const int p0 = blockIdx.x * 8;
    for (int i = tid; i < 8 * K_DIM; i += 256) wrow[i] = 0.f;
    __syncthreads();
    const int px  = tid >> 5;
    const int sub = tid & 31;
    const int p = p0 + px;
    const float x = (float)(p & 127) - 63.5f;
    const float y = (float)(p >> 7) - 63.5f;
    float* prow = &wrow[px * K_DIM];
    for (int a = sub; a < NANG; a += 32) {
        float2 c = cs[a];
        float t = fmaf(x, c.x, fmaf(y, c.y, 63.5f));
        t = fminf(fmaxf(t, 0.f), 127.f);
        float tf = fminf(floorf(t), 126.f);
        int   ti = (int)tf;
        float wt = t - tf;
        float src = ((float)a + 0.5f) * 0.0625f - 0.5f;
        src = fminf(fmaxf(src, 0.f), 7.f);
        float vf = floorf(src);
        int   v0 = (int)vf;
        int   v1 = v0 + 1 < NV ? v0 + 1 : NV - 1;
        float wa = src - vf;
        float wA0 = (1.f - wa) * OUT_SCALE;
        atomicAdd(&prow[v0 * W + ti],     wA0 * (1.f - wt));
        atomicAdd(&prow[v0 * W + ti + 1], wA0 * wt);
        if (v1 != v0) {
            float wA1 = wa * OUT_SCALE;
            atomicAdd(&prow[v1 * W + ti],     wA1 * (1.f - wt));
            atomicAdd(&prow[v1 * W + ti + 1], wA1 * wt);
        }
    }
    __syncthreads();
    // packed 2x f16 stores; block's 8192 elements are contiguous at wv + p0*K
    uint* wvu = (uint*)(wv + (size_t)p0 * K_DIM);
#pragma unroll
    for (int j = 0; j < 16; ++j) {
        int j2 = tid + 256 * j;
        float2 w2 = *(const float2*)&wrow[j2 * 2];
        union { uint u; struct { _Float16 lo, hi; } h; } pk;
        pk.h.lo = (_Float16)w2.x; pk.h.hi = (_Float16)w2.y;
        wvu[j2] = pk.u;
    }
}

// ---- kernel 3: GEMM  Out[m=row][n=pixel] = sum_k Pf[m][k] * Wv[n][k] ----
__global__ __launch_bounds__(256)
void k_gemm(const _Float16* __restrict__ A,
            const _Float16* __restrict__ B,
            float* __restrict__ out) {
    __shared__ _Float16 sA[128 * 32];
    __shared__ _Float16 sB[128 * 32];
    const int tid  = threadIdx.x;
    const int lane = tid & 63, wave = tid >> 6;
    const int m0 = blockIdx.y * 128;
    const int n0 = blockIdx.x * 128;
    const int wm = wave >> 1, wn = wave & 1;

    f32x4 acc[4][4] = {};

    const int c0 = wave * 64 + lane;
    const int c1 = c0 + 256;
    const _Float16* gA0 = A + (size_t)(m0 + (c0 >> 2)) * K_DIM + (c0 & 3) * 8;
    const _Float16* gA1 = A + (size_t)(m0 + (c1 >> 2)) * K_DIM + (c1 & 3) * 8;
    const _Float16* gB0 = B + (size_t)(n0 + (c0 >> 2)) * K_DIM + (c0 & 3) * 8;
    const _Float16* gB1 = B + (size_t)(n0 + (c1 >> 2)) * K_DIM + (c1 & 3) * 8;
    _Float16* lA0 = sA + wave * 512;
    _Float16* lA1 = sA + 2048 + wave * 512;
    _Float16* lB0 = sB + wave * 512;
    _Float16* lB1 = sB + 2048 + wave * 512;

    const int fr = lane & 15;
    const int fg = lane >> 4;

    for (int kb = 0; kb < K_DIM; kb += 32) {
        glds16(gA0 + kb, lA0);
        glds16(gA1 + kb, lA1);
        glds16(gB0 + kb, lB0);
        glds16(gB1 + kb, lB1);
        __syncthreads();
        f16x8 af[4], bf[4];
#pragma unroll
        for (int mt = 0; mt < 4; ++mt)
            af[mt] = *(const f16x8*)&sA[((wm * 4 + mt) * 16 + fr) * 32 + fg * 8];
#pragma unroll
        for (int nt = 0; nt < 4; ++nt)
            bf[nt] = *(const f16x8*)&sB[((wn * 4 + nt) * 16 + fr) * 32 + fg * 8];
#pragma unroll
        for (int mt = 0; mt < 4; ++mt)
#pragma unroll
            for (int nt = 0; nt < 4; ++nt)
                acc[mt][nt] = __builtin_amdgcn_mfma_f32_16x16x32_f16(
                    af[mt], bf[nt], acc[mt][nt], 0, 0, 0);
        __syncthreads();
    }

#pragma unroll
    for (int mt = 0; mt < 4; ++mt) {
#pragma unroll
        for (int nt = 0; nt < 4; ++nt) {
            int m = m0 + (wm * 4 + mt) * 16 + fg * 4;
            int n = n0 + (wn * 4 + nt) * 16 + fr;
            float* op = out + (size_t)m * NPIX + n;
#pragma unroll
            for (int rr = 0; rr < 4; ++rr)
                op[(size_t)rr * NPIX] = acc[mt][nt][rr];
        }
    }
}

extern "C" void kernel_launch(void* const* d_in, const int* in_sizes, int n_in,
                              void* d_out, int out_size, void* d_ws, size_t ws_size,
                              hipStream_t stream) {
    float*      kt = (float*)d_ws;
    float2*     cs = (float2*)((char*)d_ws + 512);
    _Float16*   cf = (_Float16*)((char*)d_ws + CF_OFF);
    _Float16*   pf = (_Float16*)((char*)d_ws + PF_OFF);
    _Float16*   wv = (_Float16*)((char*)d_ws + WV_OFF);

    Ptrs8 in;
    for (int i = 0; i < NV; ++i) in.p[i] = (const float*)d_in[i];

    k_tables<<<1, 128, 0, stream>>>(kt, cs, cf);
    k_fgemm<<<NROWS * NV / 64, 256, 0, stream>>>(in, cf, pf);
    k_wv<<<NPIX / 8, 256, 0, stream>>>(cs, wv);
    dim3 grid(NPIX / 128, NROWS / 128);
    k_gemm<<<grid, 256, 0, stream>>>(pf, wv, (float*)d_out);
}